// Round 2
// baseline (235.808 us; speedup 1.0000x reference)
//
#include <hip/hip_runtime.h>

typedef __bf16 bf16;
typedef __attribute__((ext_vector_type(8))) __bf16 bf16x8;
typedef __attribute__((ext_vector_type(4))) __bf16 bf16x4;
typedef __attribute__((ext_vector_type(4))) float f32x4;

// sizes: B=8, S=1024, F=512, H=8, DK=64, T = 1024-201 = 823

__device__ __forceinline__ void gload16(const void* g, void* l) {
  __builtin_amdgcn_global_load_lds(
      (const __attribute__((address_space(1))) void*)g,
      (__attribute__((address_space(3))) void*)l, 16, 0, 0);
}

// ---------------- pack weights: Bt[1536][512] = [mat|h|d][f], WOt[512][512] = WO^T ----------------
__global__ void pack_kernel(const float* __restrict__ WQ, const float* __restrict__ WK,
                            const float* __restrict__ WV, const float* __restrict__ WO,
                            bf16* __restrict__ Bt, bf16* __restrict__ WOt) {
  int idx = blockIdx.x * 256 + threadIdx.x;
  if (idx < 1536 * 512) {
    int n = idx >> 9, k = idx & 511;
    int mat = n >> 9, rem = n & 511, h = rem >> 6, d = rem & 63;
    const float* W = (mat == 0) ? WQ : ((mat == 1) ? WK : WV);
    Bt[idx] = (bf16)W[((size_t)h * 512 + k) * 64 + d];
  } else {
    int j = idx - 1536 * 512;
    int n = j >> 9, k = j & 511;
    WOt[j] = (bf16)WO[(size_t)k * 512 + n];
  }
}

// ---------------- layernorm: 1 wave per row ----------------
__global__ void ln_kernel(const float* __restrict__ x, const float* __restrict__ gam,
                          const float* __restrict__ bet, bf16* __restrict__ xn) {
  int wave = threadIdx.x >> 6, lane = threadIdx.x & 63;
  int row = blockIdx.x * 4 + wave;
  const float4* xr = (const float4*)(x + (size_t)row * 512);
  float4 v0 = xr[lane], v1 = xr[lane + 64];
  float s  = v0.x + v0.y + v0.z + v0.w + v1.x + v1.y + v1.z + v1.w;
  float s2 = v0.x * v0.x + v0.y * v0.y + v0.z * v0.z + v0.w * v0.w
           + v1.x * v1.x + v1.y * v1.y + v1.z * v1.z + v1.w * v1.w;
  #pragma unroll
  for (int m = 1; m < 64; m <<= 1) { s += __shfl_xor(s, m); s2 += __shfl_xor(s2, m); }
  float mu = s * (1.f / 512.f);
  float rstd = rsqrtf(s2 * (1.f / 512.f) - mu * mu + 1e-5f);
  const float4* gr = (const float4*)gam;
  const float4* br = (const float4*)bet;
  float4 g0 = gr[lane], g1 = gr[lane + 64], b0 = br[lane], b1 = br[lane + 64];
  bf16x4 o0, o1;
  o0[0] = (bf16)((v0.x - mu) * rstd * g0.x + b0.x);
  o0[1] = (bf16)((v0.y - mu) * rstd * g0.y + b0.y);
  o0[2] = (bf16)((v0.z - mu) * rstd * g0.z + b0.z);
  o0[3] = (bf16)((v0.w - mu) * rstd * g0.w + b0.w);
  o1[0] = (bf16)((v1.x - mu) * rstd * g1.x + b1.x);
  o1[1] = (bf16)((v1.y - mu) * rstd * g1.y + b1.y);
  o1[2] = (bf16)((v1.z - mu) * rstd * g1.z + b1.z);
  o1[3] = (bf16)((v1.w - mu) * rstd * g1.w + b1.w);
  *(bf16x4*)(xn + (size_t)row * 512 + lane * 4) = o0;
  *(bf16x4*)(xn + (size_t)row * 512 + 256 + lane * 4) = o1;
}

// ---------------- GEMM: C[M][N] = A[M][512] * Bt[N][512]^T, 128x128 tile, 4 waves ----------------
// MODE 0: QKV projection epilogue (bias + scatter to q[b,h,s,d] / k[b,h,s,d] / vt[b,h,d,s])
// MODE 1: output projection epilogue (bias + f32 out)
template <int MODE>
__global__ __launch_bounds__(256) void gemm_kernel(
    const bf16* __restrict__ A, const bf16* __restrict__ Bt, float* __restrict__ outF,
    bf16* __restrict__ qb, bf16* __restrict__ kb, bf16* __restrict__ vtb,
    const float* __restrict__ biasQ, const float* __restrict__ biasK,
    const float* __restrict__ biasV, const float* __restrict__ biasO) {
  __shared__ bf16 sA[128 * 32];
  __shared__ bf16 sB[128 * 32];
  const int tid = threadIdx.x;
  const int wave = tid >> 6, lane = tid & 63;
  const int m0 = blockIdx.x * 128, n0 = blockIdx.y * 128;
  const int wm = (wave >> 1) * 64, wn = (wave & 1) * 64;
  const int lrow = lane & 15, lk = (lane >> 4) * 8;
  const int srow = lane >> 2, scol = (lane & 3) * 8;
  f32x4 acc[4][4] = {};
  for (int kt = 0; kt < 512; kt += 32) {
    __syncthreads();
    #pragma unroll
    for (int c = 0; c < 2; ++c) {
      const int ch = wave * 2 + c;
      gload16(A + (size_t)(m0 + ch * 16 + srow) * 512 + kt + scol, &sA[ch * 512]);
      gload16(Bt + (size_t)(n0 + ch * 16 + srow) * 512 + kt + scol, &sB[ch * 512]);
    }
    __syncthreads();
    bf16x8 af[4], bfr[4];
    #pragma unroll
    for (int mi = 0; mi < 4; ++mi)
      af[mi] = *(const bf16x8*)&sA[(wm + mi * 16 + lrow) * 32 + lk];
    #pragma unroll
    for (int ni = 0; ni < 4; ++ni)
      bfr[ni] = *(const bf16x8*)&sB[(wn + ni * 16 + lrow) * 32 + lk];
    #pragma unroll
    for (int mi = 0; mi < 4; ++mi)
      #pragma unroll
      for (int ni = 0; ni < 4; ++ni)
        acc[mi][ni] = __builtin_amdgcn_mfma_f32_16x16x32_bf16(af[mi], bfr[ni], acc[mi][ni], 0, 0, 0);
  }
  if (MODE == 0) {
    #pragma unroll
    for (int ni = 0; ni < 4; ++ni) {
      const int n = n0 + wn + ni * 16 + lrow;
      const int mat = n >> 9, rem = n & 511;
      const int hh = rem >> 6, d = rem & 63;
      const float bias = (mat == 0 ? biasQ : (mat == 1 ? biasK : biasV))[rem];
      #pragma unroll
      for (int mi = 0; mi < 4; ++mi) {
        #pragma unroll
        for (int r = 0; r < 4; ++r) {
          const int m = m0 + wm + mi * 16 + (lane >> 4) * 4 + r;
          const int bb = m >> 10, ss = m & 1023;
          const float val = acc[mi][ni][r] + bias;
          if (mat == 2)
            vtb[(((size_t)bb * 8 + hh) * 64 + d) * 1024 + ss] = (bf16)val;
          else if (mat == 1)
            kb[(((size_t)bb * 8 + hh) * 1024 + ss) * 64 + d] = (bf16)val;
          else
            qb[(((size_t)bb * 8 + hh) * 1024 + ss) * 64 + d] = (bf16)val;
        }
      }
    }
  } else {
    #pragma unroll
    for (int ni = 0; ni < 4; ++ni) {
      const int n = n0 + wn + ni * 16 + lrow;
      const float bias = biasO[n];
      #pragma unroll
      for (int mi = 0; mi < 4; ++mi) {
        #pragma unroll
        for (int r = 0; r < 4; ++r) {
          const int m = m0 + wm + mi * 16 + (lane >> 4) * 4 + r;
          outF[(size_t)m * 512 + n] = acc[mi][ni][r] + bias;
        }
      }
    }
  }
}

// ---------------- flash attention with block mask, 4 waves x 16 q-rows, KV tile = 64 ----------------
__global__ __launch_bounds__(256) void attn_kernel(
    const bf16* __restrict__ qbuf, const bf16* __restrict__ kbuf,
    const bf16* __restrict__ vtbuf, bf16* __restrict__ z) {
  __shared__ bf16 pshared[4][16][64];  // per-wave P tile, XOR-swizzled columns
  const int tid = threadIdx.x;
  const int wave = tid >> 6, lane = tid & 63;
  const int bh = blockIdx.x;
  const int b = bh >> 3, h = bh & 7;
  const int q0 = blockIdx.y * 64 + wave * 16;
  const int lrow = lane & 15, lg = lane >> 4;
  const bf16* Q  = qbuf  + (size_t)bh * 1024 * 64;
  const bf16* Kp = kbuf  + (size_t)bh * 1024 * 64;
  const bf16* Vt = vtbuf + (size_t)bh * 64 * 1024;
  bf16x8 aq0, aq1;
  {
    const bf16* qs = Q + (size_t)(q0 + lrow) * 64 + lg * 8;
    aq0 = *(const bf16x8*)qs;
    aq1 = *(const bf16x8*)(qs + 32);
  }
  float mrow[4] = {-1e30f, -1e30f, -1e30f, -1e30f};
  float lsum[4] = {0.f, 0.f, 0.f, 0.f};
  f32x4 o[4] = {};
  const int qmax = blockIdx.y * 64 + 63;
  const int jend = (qmax >= 1023) ? 1024 : (qmax > 823 ? qmax : 823);
  const int ntile = (jend + 63) >> 6;
  for (int jt = 0; jt < ntile; ++jt) {
    const int j0 = jt * 64;
    f32x4 sc[4];
    #pragma unroll
    for (int ct = 0; ct < 4; ++ct) {
      const bf16* ks = Kp + (size_t)(j0 + ct * 16 + lrow) * 64 + lg * 8;
      bf16x8 kb0 = *(const bf16x8*)ks;
      bf16x8 kb1 = *(const bf16x8*)(ks + 32);
      f32x4 c = {0.f, 0.f, 0.f, 0.f};
      c = __builtin_amdgcn_mfma_f32_16x16x32_bf16(aq0, kb0, c, 0, 0, 0);
      c = __builtin_amdgcn_mfma_f32_16x16x32_bf16(aq1, kb1, c, 0, 0, 0);
      sc[ct] = c;
    }
    float tmax[4] = {-1e30f, -1e30f, -1e30f, -1e30f};
    #pragma unroll
    for (int ct = 0; ct < 4; ++ct)
      #pragma unroll
      for (int r = 0; r < 4; ++r) {
        const int i = q0 + lg * 4 + r;
        const int j = j0 + ct * 16 + lrow;
        const bool blk = (i < 823 && j >= 823) || (i >= 823 && i <= 1022 && j >= i);
        const float sv = sc[ct][r] * 0.125f + (blk ? -1e9f : 0.f);
        sc[ct][r] = sv;
        tmax[r] = fmaxf(tmax[r], sv);
      }
    #pragma unroll
    for (int r = 0; r < 4; ++r) {
      float v = tmax[r];
      v = fmaxf(v, __shfl_xor(v, 1, 16));
      v = fmaxf(v, __shfl_xor(v, 2, 16));
      v = fmaxf(v, __shfl_xor(v, 4, 16));
      v = fmaxf(v, __shfl_xor(v, 8, 16));
      tmax[r] = v;
    }
    float corr[4];
    #pragma unroll
    for (int r = 0; r < 4; ++r) {
      const float mn = fmaxf(mrow[r], tmax[r]);
      corr[r] = expf(mrow[r] - mn);
      mrow[r] = mn;
      lsum[r] *= corr[r];
    }
    #pragma unroll
    for (int nt = 0; nt < 4; ++nt)
      #pragma unroll
      for (int r = 0; r < 4; ++r) o[nt][r] *= corr[r];
    float psum[4] = {0.f, 0.f, 0.f, 0.f};
    #pragma unroll
    for (int ct = 0; ct < 4; ++ct)
      #pragma unroll
      for (int r = 0; r < 4; ++r) {
        const float p = expf(sc[ct][r] - mrow[r]);
        psum[r] += p;
        const int row = lg * 4 + r;
        pshared[wave][row][(ct * 16 + lrow) ^ ((row & 7) << 3)] = (bf16)p;
      }
    #pragma unroll
    for (int r = 0; r < 4; ++r) {
      float v = psum[r];
      v += __shfl_xor(v, 1, 16);
      v += __shfl_xor(v, 2, 16);
      v += __shfl_xor(v, 4, 16);
      v += __shfl_xor(v, 8, 16);
      lsum[r] += v;
    }
    #pragma unroll
    for (int kc = 0; kc < 2; ++kc) {
      const bf16x8 pa = *(const bf16x8*)&pshared[wave][lrow][(kc * 32 + lg * 8) ^ ((lrow & 7) << 3)];
      #pragma unroll
      for (int nt = 0; nt < 4; ++nt) {
        const bf16* vs = Vt + (size_t)(nt * 16 + lrow) * 1024 + j0 + kc * 32 + lg * 8;
        const bf16x8 vb = *(const bf16x8*)vs;
        o[nt] = __builtin_amdgcn_mfma_f32_16x16x32_bf16(pa, vb, o[nt], 0, 0, 0);
      }
    }
  }
  #pragma unroll
  for (int r = 0; r < 4; ++r) {
    const float inv = 1.f / lsum[r];
    #pragma unroll
    for (int nt = 0; nt < 4; ++nt) o[nt][r] *= inv;
  }
  #pragma unroll
  for (int nt = 0; nt < 4; ++nt)
    #pragma unroll
    for (int r = 0; r < 4; ++r) {
      const int ss = q0 + lg * 4 + r;
      z[((size_t)b * 1024 + ss) * 512 + h * 64 + nt * 16 + lrow] = (bf16)o[nt][r];
    }
}

extern "C" void kernel_launch(void* const* d_in, const int* in_sizes, int n_in,
                              void* d_out, int out_size, void* d_ws, size_t ws_size,
                              hipStream_t stream) {
  const float* x  = (const float*)d_in[0];
  const float* g  = (const float*)d_in[1];
  const float* be = (const float*)d_in[2];
  const float* WQ = (const float*)d_in[3];
  const float* bq = (const float*)d_in[4];
  const float* WK = (const float*)d_in[5];
  const float* bk = (const float*)d_in[6];
  const float* WV = (const float*)d_in[7];
  const float* bv = (const float*)d_in[8];
  const float* WO = (const float*)d_in[9];
  const float* bO = (const float*)d_in[10];
  float* out = (float*)d_out;
  char* ws = (char*)d_ws;
  // scratch layout (bytes):
  bf16* xn  = (bf16*)(ws);              // [8192][512] LN output, later reused as z
  bf16* Bt  = (bf16*)(ws + 8388608);    // [1536][512] packed QKV weights^T
  bf16* WOt = (bf16*)(ws + 9961472);    // [512][512]  WO^T
  bf16* qb  = (bf16*)(ws + 10485760);   // [8][8][1024][64]
  bf16* kb  = (bf16*)(ws + 18874368);   // [8][8][1024][64]
  bf16* vtb = (bf16*)(ws + 27262976);   // [8][8][64][1024]
  pack_kernel<<<4096, 256, 0, stream>>>(WQ, WK, WV, WO, Bt, WOt);
  ln_kernel<<<2048, 256, 0, stream>>>(x, g, be, xn);
  gemm_kernel<0><<<dim3(64, 12), 256, 0, stream>>>(xn, Bt, nullptr, qb, kb, vtb, bq, bk, bv, nullptr);
  attn_kernel<<<dim3(64, 16), 256, 0, stream>>>(qb, kb, vtb, xn /* reuse as z */);
  gemm_kernel<1><<<dim3(64, 4), 256, 0, stream>>>(xn, WOt, out, nullptr, nullptr, nullptr,
                                                  nullptr, nullptr, nullptr, bO);
}